// Round 2
// baseline (717.016 us; speedup 1.0000x reference)
//
#include <hip/hip_runtime.h>
#include <math.h>

#define B_SZ 256
#define N_TOKENS 196
#define DIM 384
#define NH 8
#define QKV_ST 1536      // NH*(2*32+128)
#define HID 1536
#define CTX_ST 1024      // NH*128
#define VT_ST 224        // padded token stride of V^T (14*16), cols 196..223 zeroed

typedef short s16x8_base __attribute__((ext_vector_type(8)));
typedef s16x8_base __attribute__((may_alias)) s16x8;
typedef float f32x4_base __attribute__((ext_vector_type(4)));
typedef f32x4_base __attribute__((may_alias)) f32x4;

__device__ inline unsigned short f2b(float f) {
  union { float f; unsigned int u; } v; v.f = f;
  unsigned int r = (v.u + 0x7FFFu + ((v.u >> 16) & 1u)) >> 16;   // RNE, finite inputs
  return (unsigned short)r;
}

// ---------------- fp32 -> bf16 convert (vectorized, grid-stride) ----------------
__global__ __launch_bounds__(256)
void cvt_f32_bf16(const float* __restrict__ in, unsigned short* __restrict__ out, int n4) {
  int i = blockIdx.x * 256 + threadIdx.x;
  const int stride = gridDim.x * 256;
  for (; i < n4; i += stride) {
    float4 v = ((const float4*)in)[i];
    ushort4 o;
    o.x = f2b(v.x); o.y = f2b(v.y); o.z = f2b(v.z); o.w = f2b(v.w);
    ((ushort4*)out)[i] = o;
  }
}

// ---------------- bf16 MFMA GEMM: C[M][N] = A[M][K] @ B[N][K]^T + bias ----------------
// 128x128 tile, BK=32, 256 threads, wave-tile 64x64 (4x4 of 16x16x32).
// Reg-staged double-buffer prefetch (round-0 known-good structure).
template <int OUT_BF16>
__global__ __launch_bounds__(256)
void gemm_bf16_bt(const unsigned short* __restrict__ A,
                  const unsigned short* __restrict__ Bm,
                  const float* __restrict__ bias,
                  void* __restrict__ C, int M, int N, int K) {
  __shared__ unsigned short As[128][32];
  __shared__ unsigned short Bs[128][32];
  const int tid = threadIdx.x;
  const int lane = tid & 63, wave = tid >> 6;
  const int quad = lane >> 4, l15 = lane & 15;
  const int ntile = N >> 7;
  const int bx = blockIdx.x % ntile, by = blockIdx.x / ntile;
  const int row0 = by << 7, col0 = bx << 7;

  const int srow = tid >> 1, soff = (tid & 1) << 4;   // staging: 32B per thread
  const unsigned short* Ag = A + (size_t)(row0 + srow) * K + soff;
  const unsigned short* Bg = Bm + (size_t)(col0 + srow) * K + soff;

  const int wr = (wave >> 1) << 6, wc = (wave & 1) << 6;

  f32x4 zero = {0.f, 0.f, 0.f, 0.f};
  f32x4 acc[4][4];
#pragma unroll
  for (int i = 0; i < 4; ++i)
#pragma unroll
    for (int j = 0; j < 4; ++j) acc[i][j] = zero;

  s16x8 a0 = *(const s16x8*)(Ag + 0);
  s16x8 a1 = *(const s16x8*)(Ag + 8);
  s16x8 b0 = *(const s16x8*)(Bg + 0);
  s16x8 b1 = *(const s16x8*)(Bg + 8);

  for (int k0 = 0; k0 < K; k0 += 32) {
    __syncthreads();
    *(s16x8*)&As[srow][soff] = a0;
    *(s16x8*)&As[srow][soff + 8] = a1;
    *(s16x8*)&Bs[srow][soff] = b0;
    *(s16x8*)&Bs[srow][soff + 8] = b1;
    __syncthreads();
    if (k0 + 32 < K) {
      a0 = *(const s16x8*)(Ag + k0 + 32);
      a1 = *(const s16x8*)(Ag + k0 + 40);
      b0 = *(const s16x8*)(Bg + k0 + 32);
      b1 = *(const s16x8*)(Bg + k0 + 40);
    }
    s16x8 af[4], bf[4];
#pragma unroll
    for (int i = 0; i < 4; ++i) {
      af[i] = *(const s16x8*)&As[wr + i * 16 + l15][quad * 8];
      bf[i] = *(const s16x8*)&Bs[wc + i * 16 + l15][quad * 8];
    }
#pragma unroll
    for (int i = 0; i < 4; ++i)
#pragma unroll
      for (int j = 0; j < 4; ++j)
        acc[i][j] = __builtin_amdgcn_mfma_f32_16x16x32_bf16(af[i], bf[j], acc[i][j], 0, 0, 0);
  }

#pragma unroll
  for (int j = 0; j < 4; ++j) {
    const int col = col0 + wc + j * 16 + l15;
    const float bj = bias[col];
#pragma unroll
    for (int i = 0; i < 4; ++i) {
      const int rowb = row0 + wr + i * 16 + quad * 4;
#pragma unroll
      for (int r = 0; r < 4; ++r) {
        float v = acc[i][j][r] + bj;
        if (OUT_BF16)
          ((unsigned short*)C)[(size_t)(rowb + r) * N + col] = f2b(v);
        else
          ((float*)C)[(size_t)(rowb + r) * N + col] = v;
      }
    }
  }
}

// ---------------- V -> V^T (per (b,h): [196][128] -> [128][224], zero-padded) ----------------
__global__ __launch_bounds__(256)
void transpose_v(const unsigned short* __restrict__ qkv, unsigned short* __restrict__ vt) {
  __shared__ unsigned short ts[32][36];
  const int id = blockIdx.x;
  const int tile = id % 28;
  const int bh = id / 28;
  const int b = bh >> 3, h = bh & 7;
  const int nt = tile % 7, dt = tile / 7;
  const int n0 = nt * 32, d0 = dt * 32;
  const int t = threadIdx.x;
  {
    const int nl = t >> 3, dq = (t & 7) << 2;
    ushort4 v4; v4.x = 0; v4.y = 0; v4.z = 0; v4.w = 0;
    if (n0 + nl < 196)
      v4 = *(const ushort4*)(qkv + ((size_t)(b * 196 + n0 + nl) * QKV_ST + h * 192 + 64 + d0 + dq));
    ts[dq + 0][nl] = v4.x; ts[dq + 1][nl] = v4.y;
    ts[dq + 2][nl] = v4.z; ts[dq + 3][nl] = v4.w;
  }
  __syncthreads();
  {
    const int dl = t >> 3, nq = (t & 7) << 2;   // n0+nq <= 220 < 224 always
    ushort4 o;
    o.x = ts[dl][nq + 0]; o.y = ts[dl][nq + 1];
    o.z = ts[dl][nq + 2]; o.w = ts[dl][nq + 3];
    *(ushort4*)(vt + ((size_t)(bh * 128 + d0 + dl) * VT_ST + n0 + nq)) = o;
  }
}

// ---------------- MFMA attention: one block per (b,h), 64-row chunks ----------------
// S = qk^T*scale + arithmetic bias (ab_s in LDS, idx = |dr|*14+|dc|), wave-local softmax,
// P (bf16) in LDS. PV transposed with PERMUTED A-rows so each lane's 8 outputs are
// contiguous in d -> single 16B store per tile, full 64B lines per instruction.
template <int NT>
__device__ __forceinline__ void attn_chunk(
    const int nc0, const unsigned short* __restrict__ qbase,
    const unsigned short* __restrict__ vgw,
    const float* __restrict__ ab_s, unsigned short* __restrict__ ctxp,
    unsigned short (*__restrict__ Pm)[232], float* __restrict__ inv_s,
    const int w, const int quad, const int l15) {
  const float scale = 0.17677669529663687f;
  f32x4 zero = {0.f, 0.f, 0.f, 0.f};

  __syncthreads();                       // Pm/inv_s free (prev chunk done)
  if (w < NT) {
    const int n0 = nc0 + w * 16;
    s16x8 aq = *(const s16x8*)(qbase + (size_t)(n0 + l15) * QKV_ST + quad * 8);
    f32x4 sacc[13];
#pragma unroll
    for (int j = 0; j < 13; ++j) {
      s16x8 bk = *(const s16x8*)(qbase + (size_t)(j * 16 + l15) * QKV_ST + 32 + quad * 8);
      sacc[j] = __builtin_amdgcn_mfma_f32_16x16x32_bf16(aq, bk, zero, 0, 0, 0);
    }
    int rn4[4], cn4[4];
#pragma unroll
    for (int r = 0; r < 4; ++r) {
      int n = n0 + quad * 4 + r;
      int nn = n < 196 ? n : 195;        // garbage rows: values irrelevant, keep idx in-bounds
      rn4[r] = nn / 14;
      cn4[r] = nn - rn4[r] * 14;
    }
    float mx[4] = {-1e30f, -1e30f, -1e30f, -1e30f};
#pragma unroll
    for (int j = 0; j < 13; ++j) {
      const int m = j * 16 + l15;
      const int mm = m < 196 ? m : 195;
      const int rm = mm / 14;
      const int cm = mm - rm * 14;
#pragma unroll
      for (int r = 0; r < 4; ++r) {
        int dr = rn4[r] - rm; dr = dr < 0 ? -dr : dr;
        int dc = cn4[r] - cm; dc = dc < 0 ? -dc : dc;
        float s = fmaf(sacc[j][r], scale, ab_s[dr * 14 + dc]);
        if (j == 12) s = (l15 < 4) ? s : -1e30f;   // NaN-safe m-mask (garbage K rows)
        sacc[j][r] = s;
        mx[r] = fmaxf(mx[r], s);
      }
    }
#pragma unroll
    for (int o = 8; o > 0; o >>= 1)
#pragma unroll
      for (int r = 0; r < 4; ++r) mx[r] = fmaxf(mx[r], __shfl_xor(mx[r], o));
    const int prow = w * 16 + quad * 4;
    float sm[4] = {0.f, 0.f, 0.f, 0.f};
#pragma unroll
    for (int j = 0; j < 13; ++j) {
#pragma unroll
      for (int r = 0; r < 4; ++r) {
        float e = __expf(sacc[j][r] - mx[r]);
        sm[r] += e;
        Pm[prow + r][j * 16 + l15] = f2b(e);
      }
    }
#pragma unroll
    for (int o = 8; o > 0; o >>= 1)
#pragma unroll
      for (int r = 0; r < 4; ++r) sm[r] += __shfl_xor(sm[r], o);
    if (l15 == 0) {
#pragma unroll
      for (int r = 0; r < 4; ++r) inv_s[prow + r] = 1.f / sm[r];
    }
  }
  __syncthreads();                       // P + inv_s ready

  // PV (transposed, permuted A-rows): wave owns d in [w*32, w*32+32); no barriers.
  f32x4 acc0[NT], acc1[NT];
#pragma unroll
  for (int i = 0; i < NT; ++i) { acc0[i] = zero; acc1[i] = zero; }
#pragma unroll
  for (int ks = 0; ks < 7; ++ks) {
    s16x8 va0 = *(const s16x8*)(vgw + ks * 32);                // rows perm(l15)
    s16x8 va1 = *(const s16x8*)(vgw + 4 * VT_ST + ks * 32);    // rows perm(l15)+4
#pragma unroll
    for (int i = 0; i < NT; ++i) {
      s16x8 pb = *(const s16x8*)&Pm[i * 16 + l15][ks * 32 + quad * 8];
      acc0[i] = __builtin_amdgcn_mfma_f32_16x16x32_bf16(va0, pb, acc0[i], 0, 0, 0);
      acc1[i] = __builtin_amdgcn_mfma_f32_16x16x32_bf16(va1, pb, acc1[i], 0, 0, 0);
    }
  }
  // epilogue: lane holds d = w*32 + quad*8 + {0..7} for n = nc0+i*16+l15 -> one 16B store
#pragma unroll
  for (int i = 0; i < NT; ++i) {
    const int n = nc0 + i * 16 + l15;
    if (n < 196) {
      const float is = inv_s[i * 16 + l15];
      s16x8 o;
      o[0] = (short)f2b(acc0[i][0] * is); o[1] = (short)f2b(acc0[i][1] * is);
      o[2] = (short)f2b(acc0[i][2] * is); o[3] = (short)f2b(acc0[i][3] * is);
      o[4] = (short)f2b(acc1[i][0] * is); o[5] = (short)f2b(acc1[i][1] * is);
      o[6] = (short)f2b(acc1[i][2] * is); o[7] = (short)f2b(acc1[i][3] * is);
      *(s16x8*)(ctxp + (size_t)n * CTX_ST + w * 32 + quad * 8) = o;
    }
  }
}

__global__ __launch_bounds__(256, 4)
void attn_mfma(const unsigned short* __restrict__ qkv,
               const unsigned short* __restrict__ vt,
               const float* __restrict__ ab,
               unsigned short* __restrict__ ctx) {
  __shared__ unsigned short Pm[64][232];   // 64-row P chunk; cols 208..223 read by PV tail
  __shared__ float inv_s[64];
  __shared__ float ab_s[196];

  const int bh = blockIdx.x;
  const int b = bh >> 3, h = bh & 7;
  const int tid = threadIdx.x;
  const int lane = tid & 63, w = tid >> 6;
  const int quad = lane >> 4, l15 = lane & 15;

  const unsigned short* qbase = qkv + (size_t)b * N_TOKENS * QKV_ST + h * 192;
  // permuted A-row: lane l15 loads physical d-row perm(l15) = (l15&3) + (l15>>2)*8
  const int pr = (l15 & 3) + ((l15 >> 2) << 3);
  const unsigned short* vgw = vt + ((size_t)bh * 128 + w * 32 + pr) * VT_ST + quad * 8;
  unsigned short* ctxp = ctx + (size_t)b * N_TOKENS * CTX_ST + h * 128;

  if (tid < 196) ab_s[tid] = ab[h * 196 + tid];
  if (tid < 64) {                       // zero PV-tail pad cols once (never clobbered)
    ushort4 z; z.x = 0; z.y = 0; z.z = 0; z.w = 0;
#pragma unroll
    for (int c = 208; c < 232; c += 4) *(ushort4*)&Pm[tid][c] = z;
  }

#pragma unroll 1
  for (int c = 0; c < 3; ++c)
    attn_chunk<4>(c * 64, qbase, vgw, ab_s, ctxp, Pm, inv_s, w, quad, l15);
  attn_chunk<1>(192, qbase, vgw, ab_s, ctxp, Pm, inv_s, w, quad, l15);
}

extern "C" void kernel_launch(void* const* d_in, const int* in_sizes, int n_in,
                              void* d_out, int out_size, void* d_ws, size_t ws_size,
                              hipStream_t stream) {
  const float* x     = (const float*)d_in[0];
  const float* Wqkv  = (const float*)d_in[1];
  const float* bqkv  = (const float*)d_in[2];
  const float* Wproj = (const float*)d_in[3];
  const float* bproj = (const float*)d_in[4];
  const float* ab    = (const float*)d_in[5];
  float* out = (float*)d_out;

  const size_t szWq = 589824, szWp = 393216, szX = (size_t)B_SZ * N_TOKENS * DIM;
  const size_t fixedB = (szWq + szWp + szX) * 2;
  // per-batch: vt 8*128*224 + qkv 196*1536 + ctx 196*1024 elements (bf16)
  const size_t perB = (229376ULL + 301056ULL + 200704ULL) * 2;
  int Bs = 256;
  while (Bs > 32 && fixedB + (size_t)Bs * perB > ws_size) Bs >>= 1;

  unsigned short* Wqb  = (unsigned short*)d_ws;
  unsigned short* Wpb  = Wqb + szWq;
  unsigned short* xb   = Wpb + szWp;
  unsigned short* vtb  = xb + szX;
  unsigned short* qkvb = vtb + (size_t)Bs * 229376;
  unsigned short* ctxb = qkvb + (size_t)Bs * 301056;

  cvt_f32_bf16<<<dim3(576), dim3(256), 0, stream>>>(Wqkv, Wqb, (int)(szWq / 4));
  cvt_f32_bf16<<<dim3(384), dim3(256), 0, stream>>>(Wproj, Wpb, (int)(szWp / 4));
  cvt_f32_bf16<<<dim3(4096), dim3(256), 0, stream>>>(x, xb, (int)(szX / 4));

  const int nslice = B_SZ / Bs;
  const int Ms = Bs * N_TOKENS;
  for (int s = 0; s < nslice; ++s) {
    const unsigned short* xs = xb + (size_t)s * Ms * DIM;
    float* outs = out + (size_t)s * Ms * DIM;
    gemm_bf16_bt<1><<<dim3((Ms / 128) * (HID / 128)), dim3(256), 0, stream>>>(
        xs, Wqb, bqkv, qkvb, Ms, HID, DIM);
    transpose_v<<<dim3(Bs * 8 * 28), dim3(256), 0, stream>>>(qkvb, vtb);
    attn_mfma<<<dim3(Bs * 8), dim3(256), 0, stream>>>(qkvb, vtb, ab, ctxb);
    gemm_bf16_bt<0><<<dim3((Ms / 128) * (DIM / 128)), dim3(256), 0, stream>>>(
        ctxb, Wpb, bproj, outs, Ms, DIM, CTX_ST);
  }
}